// Round 1
// baseline (109.408 us; speedup 1.0000x reference)
//
#include <hip/hip_runtime.h>
#include <math.h>

#define BB 16
#define NN 8400
#define CC 80
#define MM 64
#define KTOP 13
#define FEPS 1e-9f

// ---- output layout (floats) ----
// O0 target_labels : [B,N]      off 0        size 134400
// O1 target_bboxes : [B,N,4]    off 134400   size 537600
// O2 cls_targets   : [B,N,C]    off 672000   size 10752000
// O3 fg_mask       : [B,N]      off 11424000 size 134400
// O4 tgt_gt_idx    : [B,N]      off 11558400 size 134400
#define OFF_O1 134400
#define OFF_O2 672000
#define OFF_O3 11424000
#define OFF_O4 11558400

__device__ __forceinline__ float iou_pair(const float4 g, const float4 p) {
    float ix1 = fmaxf(g.x, p.x);
    float iy1 = fmaxf(g.y, p.y);
    float ix2 = fminf(g.z, p.z);
    float iy2 = fminf(g.w, p.w);
    float iw = fmaxf(ix2 - ix1, 0.0f);
    float ih = fmaxf(iy2 - iy1, 0.0f);
    float inter = iw * ih;
    float aa = (g.z - g.x) * (g.w - g.y);
    float ab = (p.z - p.x) * (p.w - p.y);
    float uni = fmaxf(aa + ab - inter, FEPS);
    return inter / uni;
}

// Kernel 1: one workgroup per (b,m). Compute align row, store it, find 13th-largest value.
__global__ __launch_bounds__(256) void k_align(
    const float* __restrict__ pd_scores, const float* __restrict__ pd_bboxes,
    const float* __restrict__ anc, const int* __restrict__ gt_labels,
    const float* __restrict__ gt_bboxes, const float* __restrict__ mask_gt,
    float* __restrict__ align_buf, float* __restrict__ thr_buf)
{
    const int bm = blockIdx.x;
    const int b = bm / MM, m = bm % MM;
    const int tid = threadIdx.x;

    __shared__ float sval[NN];    // 33.6 KB
    __shared__ float rv[256];
    __shared__ int   ri[256];

    const float4 g = *(const float4*)&gt_bboxes[(size_t)(b*MM + m) * 4];
    const int lab   = gt_labels[b*MM + m];
    const int labc  = lab > 0 ? lab : 0;
    const bool mgb  = mask_gt[b*MM + m] > 0.5f;

    const float* srow = pd_scores + (size_t)b * NN * CC + labc;
    const float* pbb  = pd_bboxes + (size_t)b * NN * 4;

    for (int n = tid; n < NN; n += 256) {
        float ax = anc[2*n], ay = anc[2*n + 1];
        float d1 = ax - g.x, d2 = ay - g.y, d3 = g.z - ax, d4 = g.w - ay;
        float mind = fminf(fminf(d1, d2), fminf(d3, d4));
        bool valid = (mind > FEPS) && mgb;
        float a = 0.0f;
        if (valid) {
            float4 p = *(const float4*)&pbb[(size_t)n * 4];
            float i = iou_pair(g, p);
            float x = srow[(size_t)n * CC];
            float s = 1.0f / (1.0f + expf(-x));
            float i2 = i * i;
            a = s * (i2 * i2 * i2);
        }
        align_buf[(size_t)bm * NN + n] = a;
        sval[n] = a;
    }
    __syncthreads();

    // 13 iterations of parallel argmax + removal; only the 13th value is needed.
    float v13 = 0.0f;
    for (int it = 0; it < KTOP; ++it) {
        float bv = -1.0f; int bi = 0;
        for (int n = tid; n < NN; n += 256) {
            float v = sval[n];
            if (v > bv) { bv = v; bi = n; }
        }
        rv[tid] = bv; ri[tid] = bi;
        __syncthreads();
        for (int s = 128; s > 0; s >>= 1) {
            if (tid < s && rv[tid + s] > rv[tid]) { rv[tid] = rv[tid + s]; ri[tid] = ri[tid + s]; }
            __syncthreads();
        }
        v13 = rv[0];
        if (tid == 0) sval[ri[0]] = -1.0f;
        __syncthreads();
    }
    if (tid == 0) thr_buf[bm] = v13;
}

// Kernel 2: one thread per (b,n) anchor. Resolve assignment, write O0/O1/O3/O4 + per_anchor.
__global__ __launch_bounds__(256) void k_assign(
    const float* __restrict__ pd_bboxes, const float* __restrict__ anc,
    const int* __restrict__ gt_labels, const float* __restrict__ gt_bboxes,
    const float* __restrict__ mask_gt,
    const float* __restrict__ align_buf, const float* __restrict__ thr_buf,
    float* __restrict__ out0, float* __restrict__ out1,
    float* __restrict__ out3, float* __restrict__ out4,
    float* __restrict__ per_buf)
{
    const int b = blockIdx.y;
    const int n = blockIdx.x * 256 + threadIdx.x;

    __shared__ float4 gtb[MM];
    __shared__ float  thrS[MM];
    __shared__ int    labS[MM];
    __shared__ float  mgS[MM];
    if (threadIdx.x < MM) {
        int m = threadIdx.x;
        gtb[m]  = *(const float4*)&gt_bboxes[(size_t)(b*MM + m) * 4];
        thrS[m] = thr_buf[b*MM + m];
        labS[m] = gt_labels[b*MM + m];
        mgS[m]  = mask_gt[b*MM + m];
    }
    __syncthreads();
    if (n >= NN) return;

    const float4 p = *(const float4*)&pd_bboxes[((size_t)b * NN + n) * 4];
    const float ax = anc[2*n], ay = anc[2*n + 1];

    int posCount = 0;
    int firstM = -1; float firstA = 0.0f, firstI = 0.0f;
    float bestI = -1.0f; int bestM = 0; float bestA = 0.0f;

    for (int m = 0; m < MM; ++m) {
        float a = align_buf[((size_t)(b*MM + m)) * NN + n];  // coalesced across lanes
        float4 g = gtb[m];
        float d1 = ax - g.x, d2 = ay - g.y, d3 = g.z - ax, d4 = g.w - ay;
        bool valid = (fminf(fminf(d1, d2), fminf(d3, d4)) > FEPS) && (mgS[m] > 0.5f);
        float i = valid ? iou_pair(g, p) : 0.0f;
        bool pos = (a > FEPS) && (a >= thrS[m]);
        if (pos) {
            ++posCount;
            if (firstM < 0) { firstM = m; firstA = a; firstI = i; }
        }
        if (i > bestI) { bestI = i; bestM = m; bestA = a; }  // first-max wins (strict >)
    }

    int mstar; float fg, per;
    if (posCount > 1) {
        mstar = bestM;
        per = (bestA / (bestA + FEPS)) * bestI;
        fg = 1.0f;
    } else if (posCount == 1) {
        mstar = firstM;
        per = (firstA / (firstA + FEPS)) * firstI;
        fg = 1.0f;
    } else {
        mstar = 0; per = 0.0f; fg = 0.0f;
    }

    const size_t idx = (size_t)b * NN + n;
    out0[idx] = (float)labS[mstar];
    ((float4*)out1)[idx] = gtb[mstar];
    out3[idx] = fg;
    out4[idx] = (float)mstar;
    per_buf[idx] = per;
}

// Kernel 3a: zero cls_targets region (float4-coalesced).
__global__ __launch_bounds__(256) void k_zero(float4* __restrict__ p, int n4)
{
    int i = blockIdx.x * 256 + threadIdx.x;
    if (i < n4) p[i] = make_float4(0.f, 0.f, 0.f, 0.f);
}

// Kernel 3b: scatter per_anchor into cls_targets at target label.
__global__ __launch_bounds__(256) void k_scatter(
    const float* __restrict__ out0, const float* __restrict__ per_buf,
    float* __restrict__ cls)
{
    int i = blockIdx.x * 256 + threadIdx.x;
    if (i < BB * NN) {
        int lab = (int)out0[i];
        float per = per_buf[i];
        if (lab >= 0 && lab < CC) cls[(size_t)i * CC + lab] = per;
    }
}

extern "C" void kernel_launch(void* const* d_in, const int* in_sizes, int n_in,
                              void* d_out, int out_size, void* d_ws, size_t ws_size,
                              hipStream_t stream) {
    const float* pd_scores = (const float*)d_in[0];
    const float* pd_bboxes = (const float*)d_in[1];
    const float* anc       = (const float*)d_in[2];
    const int*   gt_labels = (const int*)d_in[3];
    const float* gt_bboxes = (const float*)d_in[4];
    const float* mask_gt   = (const float*)d_in[5];

    float* out  = (float*)d_out;
    float* out0 = out;
    float* out1 = out + OFF_O1;
    float* out2 = out + OFF_O2;   // cls_targets; also reused as align scratch
    float* out3 = out + OFF_O3;
    float* out4 = out + OFF_O4;

    float* thr_buf = (float*)d_ws;             // B*M = 1024 floats
    float* per_buf = thr_buf + 1024;           // B*N = 134400 floats

    float* align_buf = out2;                   // B*M*N = 8,601,600 floats <= 10,752,000

    // 1) align metric + per-row 13th-largest threshold
    k_align<<<dim3(BB * MM), dim3(256), 0, stream>>>(
        pd_scores, pd_bboxes, anc, gt_labels, gt_bboxes, mask_gt, align_buf, thr_buf);

    // 2) per-anchor resolution (reads align_buf from the cls region)
    k_assign<<<dim3((NN + 255) / 256, BB), dim3(256), 0, stream>>>(
        pd_bboxes, anc, gt_labels, gt_bboxes, mask_gt, align_buf, thr_buf,
        out0, out1, out3, out4, per_buf);

    // 3) zero cls region, then scatter one-hot * per_anchor
    const int n4 = (BB * NN * CC) / 4;         // 2,688,000 float4s
    k_zero<<<dim3((n4 + 255) / 256), dim3(256), 0, stream>>>((float4*)out2, n4);
    k_scatter<<<dim3((BB * NN + 255) / 256), dim3(256), 0, stream>>>(out0, per_buf, out2);
}

// Round 3
// 106.252 us; speedup vs baseline: 1.0297x; 1.0297x over previous
//
#include <hip/hip_runtime.h>
#include <math.h>

#define BB 16
#define NN 8400
#define CC 80
#define MM 64
#define KTOP 13
#define FEPS 1e-9f
#define NITER 33   // ceil(NN/256)

// ---- output layout (floats) ----
// O0 target_labels : [B,N]      off 0        size 134400
// O1 target_bboxes : [B,N,4]    off 134400   size 537600
// O2 cls_targets   : [B,N,C]    off 672000   size 10752000
// O3 fg_mask       : [B,N]      off 11424000 size 134400
// O4 tgt_gt_idx    : [B,N]      off 11558400 size 134400
#define OFF_O1 134400
#define OFF_O2 672000
#define OFF_O3 11424000
#define OFF_O4 11558400
// scratch (cnt/msel/asel, 3 x B*N) in the TAIL of the cls region; read by
// k_assign, then fully overwritten by k_cls afterwards (stream order).
#define SCR_OFF 10348800   // 10,752,000 - 3*134,400

__device__ __forceinline__ float iou_pair(const float4 g, const float4 p) {
    float ix1 = fmaxf(g.x, p.x);
    float iy1 = fmaxf(g.y, p.y);
    float ix2 = fminf(g.z, p.z);
    float iy2 = fminf(g.w, p.w);
    float iw = fmaxf(ix2 - ix1, 0.0f);
    float ih = fmaxf(iy2 - iy1, 0.0f);
    float inter = iw * ih;
    float aa = (g.z - g.x) * (g.w - g.y);
    float ab = (p.z - p.x) * (p.w - p.y);
    float uni = fmaxf(aa + ab - inter, FEPS);
    return inter / uni;
}

__global__ __launch_bounds__(256) void k_zero_scratch(int* __restrict__ p, int n)
{
    int i = blockIdx.x * 256 + threadIdx.x;
    if (i < n) p[i] = 0;
}

// Kernel 1: one workgroup per (b,m). Deterministic compaction of valid anchors
// (sorted by n), align only for those, top-13 with (value, slot) lexicographic
// tie-break (== jax top_k stability), scatter <=13 positives via atomics.
__global__ __launch_bounds__(256) void k_select(
    const float* __restrict__ pd_scores, const float* __restrict__ pd_bboxes,
    const float* __restrict__ anc, const int* __restrict__ gt_labels,
    const float* __restrict__ gt_bboxes, const float* __restrict__ mask_gt,
    int* __restrict__ cntb, int* __restrict__ mselb, float* __restrict__ aselb)
{
    const int bm = blockIdx.x;
    const int b = bm >> 6, m = bm & 63;
    const int tid = threadIdx.x;
    const int lane = tid & 63;
    const int wid = tid >> 6;

    __shared__ float aval[NN];            // 33.6 KB (compacted align values)
    __shared__ unsigned short sidx[NN];   // 16.8 KB (compacted anchor indices)
    __shared__ int wcnt[NITER * 4];       // per-(iter,wave) counts -> offsets
    __shared__ int scnt;
    __shared__ float wrv[4];
    __shared__ int   wri[4];
    __shared__ float top_v[KTOP];
    __shared__ int   top_i[KTOP];

    const float4 g = *(const float4*)&gt_bboxes[(size_t)bm * 4];
    const int lab  = gt_labels[bm];
    const int labc = lab > 0 ? lab : 0;
    const bool mgb = mask_gt[bm] > 0.5f;

    // pass 0: per-(iter,wave) valid counts (exec-uniform, full-wave ballots)
    unsigned long long myvalid = 0ull;
    for (int it = 0; it < NITER; ++it) {
        int n = it * 256 + tid;
        bool valid = false;
        if (n < NN) {
            float2 a2 = *(const float2*)&anc[2 * n];
            float d1 = a2.x - g.x, d2 = a2.y - g.y;
            float d3 = g.z - a2.x, d4 = g.w - a2.y;
            valid = (fminf(fminf(d1, d2), fminf(d3, d4)) > FEPS) && mgb;
        }
        if (valid) myvalid |= (1ull << it);
        unsigned long long bal = __ballot(valid);
        if (lane == 0) wcnt[it * 4 + wid] = __popcll(bal);
    }
    __syncthreads();

    // exclusive prefix over the 132 (iter,wave) chunks — deterministic offsets
    if (tid == 0) {
        int s = 0;
        for (int j = 0; j < NITER * 4; ++j) { int c = wcnt[j]; wcnt[j] = s; s += c; }
        scnt = s;
    }
    __syncthreads();

    // pass 1b: write compacted indices (sidx ends up sorted ascending by n)
    for (int it = 0; it < NITER; ++it) {
        bool valid = (myvalid >> it) & 1ull;
        unsigned long long bal = __ballot(valid);
        if (valid) {
            int pfx = __popcll(bal & ((1ull << lane) - 1ull));
            sidx[wcnt[it * 4 + wid] + pfx] = (unsigned short)(it * 256 + tid);
        }
    }
    __syncthreads();
    const int count = scnt;

    // pass 2: align metric only for compacted entries (~400 of 8400)
    const float* srow = pd_scores + (size_t)b * NN * CC + labc;
    const float* pbb  = pd_bboxes + (size_t)b * NN * 4;
    for (int i = tid; i < count; i += 256) {
        int n = sidx[i];
        float4 p = *(const float4*)&pbb[(size_t)n * 4];
        float io = iou_pair(g, p);
        float x = srow[(size_t)n * CC];
        float s = 1.0f / (1.0f + expf(-x));
        float i2 = io * io;
        aval[i] = s * (i2 * i2 * i2);
    }
    __syncthreads();

    // 13 rounds of argmax + record + remove; ties -> smaller slot (smaller n)
    for (int it = 0; it < KTOP; ++it) {
        float bv = -1.0f; int bi = -1;
        for (int i = tid; i < count; i += 256) {
            float v = aval[i];
            if (v >= 0.0f && (v > bv || (v == bv && i < bi) || bi < 0)) {
                if (v > bv || bi < 0 || (v == bv && i < bi)) { bv = v; bi = i; }
            }
        }
        #pragma unroll
        for (int off = 32; off > 0; off >>= 1) {
            float ov = __shfl_down(bv, off, 64);
            int   oi = __shfl_down(bi, off, 64);
            // invariant: value==-1 <=> slot==-1; equal nonneg values have nonneg slots
            if (ov > bv || (ov == bv && oi >= 0 && (bi < 0 || oi < bi))) { bv = ov; bi = oi; }
        }
        if (lane == 0) { wrv[wid] = bv; wri[wid] = bi; }
        __syncthreads();
        if (tid == 0) {
            float fb = wrv[0]; int fi = wri[0];
            for (int w = 1; w < 4; ++w) {
                float ov = wrv[w]; int oi = wri[w];
                if (ov > fb || (ov == fb && oi >= 0 && (fi < 0 || oi < fi))) { fb = ov; fi = oi; }
            }
            top_v[it] = fb; top_i[it] = fi;
            if (fi >= 0) aval[fi] = -1.0f;   // remove (real values are >= 0)
        }
        __syncthreads();
    }

    // emit positives: recorded top entries with value > EPS (<=13 per row)
    if (tid < KTOP) {
        float v = top_v[tid];
        int i = top_i[tid];
        if (i >= 0 && v > FEPS) {
            int n = sidx[i];
            int ai = b * NN + n;
            atomicAdd(&cntb[ai], 1);
            atomicAdd(&mselb[ai], m);
            atomicAdd(&aselb[ai], v);
        }
    }
}

// Kernel 2: one thread per (b,n). Resolve assignment from scattered positives.
__global__ __launch_bounds__(256) void k_assign(
    const float* __restrict__ pd_scores, const float* __restrict__ pd_bboxes,
    const float* __restrict__ anc, const int* __restrict__ gt_labels,
    const float* __restrict__ gt_bboxes, const float* __restrict__ mask_gt,
    const int* __restrict__ cntb, const int* __restrict__ mselb,
    const float* __restrict__ aselb,
    float* __restrict__ out0, float* __restrict__ out1,
    float* __restrict__ out3, float* __restrict__ out4,
    float* __restrict__ perb)
{
    const int b = blockIdx.y;
    const int n = blockIdx.x * 256 + threadIdx.x;

    __shared__ float4 gtb[MM];
    __shared__ int    labS[MM];
    __shared__ float  mgS[MM];
    if (threadIdx.x < MM) {
        int m = threadIdx.x;
        gtb[m]  = *(const float4*)&gt_bboxes[(size_t)(b * MM + m) * 4];
        labS[m] = gt_labels[b * MM + m];
        mgS[m]  = mask_gt[b * MM + m];
    }
    __syncthreads();
    if (n >= NN) return;

    const size_t idx = (size_t)b * NN + n;
    const int cnt = cntb[idx];

    float per = 0.0f, fg = 0.0f;
    int mstar = 0;

    if (cnt > 0) {
        fg = 1.0f;
        const float4 p = *(const float4*)&pd_bboxes[idx * 4];
        if (cnt == 1) {
            mstar = mselb[idx];
            float a = aselb[idx];
            float io = iou_pair(gtb[mstar], p);   // positive => valid
            per = a / (a + FEPS) * io;
        } else {
            // multi-assigned: reference resolves by argmax IoU over valid m
            float2 a2 = *(const float2*)&anc[2 * n];
            float bestI = -1.0f; int bestM = 0;
            for (int m = 0; m < MM; ++m) {
                float4 gg = gtb[m];
                float d1 = a2.x - gg.x, d2 = a2.y - gg.y;
                float d3 = gg.z - a2.x, d4 = gg.w - a2.y;
                bool valid = (fminf(fminf(d1, d2), fminf(d3, d4)) > FEPS) &&
                             (mgS[m] > 0.5f);
                float io = valid ? iou_pair(gg, p) : 0.0f;
                if (io > bestI) { bestI = io; bestM = m; }   // first-max wins
            }
            mstar = bestM;
            float io = bestI;
            int lb = labS[mstar]; int lbc = lb > 0 ? lb : 0;
            float x = pd_scores[idx * CC + lbc];
            float s = 1.0f / (1.0f + expf(-x));
            float i2 = io * io;
            float a = s * (i2 * i2 * i2);      // continuous-only recompute
            per = a / (a + FEPS) * io;
        }
    }

    out0[idx] = (float)labS[mstar];
    ((float4*)out1)[idx] = gtb[mstar];
    out3[idx] = fg;
    out4[idx] = (float)mstar;
    perb[idx] = per;
}

// Kernel 3: fused zero + one-hot scatter, dense coalesced float4 writes.
__global__ __launch_bounds__(256) void k_cls(
    const float* __restrict__ out0, const float* __restrict__ perb,
    float4* __restrict__ cls4)
{
    int i = blockIdx.x * 256 + threadIdx.x;      // float4 index, C/4 = 20 per row
    if (i >= BB * NN * CC / 4) return;
    int row = i / 20;
    int c4 = (i - row * 20) * 4;
    int lab = (int)out0[row];
    float per = perb[row];
    int d = lab - c4;
    float4 v;
    v.x = (d == 0) ? per : 0.0f;
    v.y = (d == 1) ? per : 0.0f;
    v.z = (d == 2) ? per : 0.0f;
    v.w = (d == 3) ? per : 0.0f;
    cls4[i] = v;
}

extern "C" void kernel_launch(void* const* d_in, const int* in_sizes, int n_in,
                              void* d_out, int out_size, void* d_ws, size_t ws_size,
                              hipStream_t stream) {
    const float* pd_scores = (const float*)d_in[0];
    const float* pd_bboxes = (const float*)d_in[1];
    const float* anc       = (const float*)d_in[2];
    const int*   gt_labels = (const int*)d_in[3];
    const float* gt_bboxes = (const float*)d_in[4];
    const float* mask_gt   = (const float*)d_in[5];

    float* out  = (float*)d_out;
    float* out0 = out;
    float* out1 = out + OFF_O1;
    float* out2 = out + OFF_O2;
    float* out3 = out + OFF_O3;
    float* out4 = out + OFF_O4;

    // scratch in cls-region tail (overwritten by k_cls at the end)
    float* scr   = out2 + SCR_OFF;
    int*   cntb  = (int*)scr;
    int*   mselb = (int*)(scr + 134400);
    float* aselb = scr + 268800;
    float* perb  = (float*)d_ws;               // B*N floats

    // 0) zero the atomic scratch
    k_zero_scratch<<<dim3((403200 + 255) / 256), dim3(256), 0, stream>>>(
        (int*)scr, 403200);

    // 1) per-(b,m): deterministic compact, align, top-13, scatter positives
    k_select<<<dim3(BB * MM), dim3(256), 0, stream>>>(
        pd_scores, pd_bboxes, anc, gt_labels, gt_bboxes, mask_gt,
        cntb, mselb, aselb);

    // 2) per-anchor resolution
    k_assign<<<dim3((NN + 255) / 256, BB), dim3(256), 0, stream>>>(
        pd_scores, pd_bboxes, anc, gt_labels, gt_bboxes, mask_gt,
        cntb, mselb, aselb, out0, out1, out3, out4, perb);

    // 3) cls_targets: fused zero + scatter (dense coalesced write)
    const int n4 = (BB * NN * CC) / 4;
    k_cls<<<dim3((n4 + 255) / 256), dim3(256), 0, stream>>>(out0, perb, (float4*)out2);
}

// Round 4
// 63.148 us; speedup vs baseline: 1.7326x; 1.6826x over previous
//
#include <hip/hip_runtime.h>
#include <math.h>

#define BB 16
#define NN 8400
#define CC 80
#define MM 64
#define KTOP 13
#define FEPS 1e-9f
#define NITER 33   // ceil(NN/256)
#define CAP 2048   // max valid anchors per (b,m): worst-case ~1500

// ---- output layout (floats) ----
#define OFF_O1 134400
#define OFF_O2 672000
#define OFF_O3 11424000
#define OFF_O4 11558400
// scratch (cnt/msel/asel, 3 x B*N) in the TAIL of the cls region; read by
// k_assign, then fully overwritten by k_cls afterwards (stream order).
#define SCR_OFF 10348800   // 10,752,000 - 3*134,400

__device__ __forceinline__ float iou_pair(const float4 g, const float4 p) {
    float ix1 = fmaxf(g.x, p.x);
    float iy1 = fmaxf(g.y, p.y);
    float ix2 = fminf(g.z, p.z);
    float iy2 = fminf(g.w, p.w);
    float iw = fmaxf(ix2 - ix1, 0.0f);
    float ih = fmaxf(iy2 - iy1, 0.0f);
    float inter = iw * ih;
    float aa = (g.z - g.x) * (g.w - g.y);
    float ab = (p.z - p.x) * (p.w - p.y);
    float uni = fmaxf(aa + ab - inter, FEPS);
    return inter / uni;
}

__global__ __launch_bounds__(256) void k_zero_scratch(int* __restrict__ p, int n)
{
    int i = blockIdx.x * 256 + threadIdx.x;
    if (i < n) p[i] = 0;
}

// Kernel 1: one workgroup per (b,m). Atomic-append compaction (order-free),
// align for compacted entries, exact 13th-largest via 4-bit radix-select
// (order-invariant), n-based tie cut, scatter <=13 positives via atomics.
__global__ __launch_bounds__(256) void k_select(
    const float* __restrict__ pd_scores, const float* __restrict__ pd_bboxes,
    const float* __restrict__ anc, const int* __restrict__ gt_labels,
    const float* __restrict__ gt_bboxes, const float* __restrict__ mask_gt,
    int* __restrict__ cntb, int* __restrict__ mselb, float* __restrict__ aselb)
{
    const int bm = blockIdx.x;
    const int b = bm >> 6, m = bm & 63;
    const int tid = threadIdx.x;

    __shared__ unsigned keys[CAP];        // 8 KB: align float bits (>=0)
    __shared__ unsigned short nnidx[CAP]; // 4 KB: anchor index
    __shared__ int hist[16];
    __shared__ int scnt, scount;
    __shared__ unsigned sprefix;
    __shared__ int sk, sE;

    const float4 g = *(const float4*)&gt_bboxes[(size_t)bm * 4];
    const int lab  = gt_labels[bm];
    const int labc = lab > 0 ? lab : 0;
    const bool mgb = mask_gt[bm] > 0.5f;
    const unsigned epskey = __float_as_uint(FEPS);

    if (tid == 0) scnt = 0;
    __syncthreads();

    // pass 1: in-box test + atomic-append of valid anchor indices (any order)
    for (int it = 0; it < NITER; ++it) {
        int n = it * 256 + tid;
        bool valid = false;
        if (n < NN) {
            float2 a2 = *(const float2*)&anc[2 * n];
            float d1 = a2.x - g.x, d2 = a2.y - g.y;
            float d3 = g.z - a2.x, d4 = g.w - a2.y;
            valid = (fminf(fminf(d1, d2), fminf(d3, d4)) > FEPS) && mgb;
        }
        if (valid) {
            int slot = atomicAdd(&scnt, 1);
            if (slot < CAP) nnidx[slot] = (unsigned short)n;
        }
    }
    __syncthreads();
    const int count = min(scnt, CAP);

    // pass 2: align metric for compacted entries (~400)
    const float* srow = pd_scores + (size_t)b * NN * CC + labc;
    const float* pbb  = pd_bboxes + (size_t)b * NN * 4;
    for (int i = tid; i < count; i += 256) {
        int n = nnidx[i];
        float4 p = *(const float4*)&pbb[(size_t)n * 4];
        float io = iou_pair(g, p);
        float x = srow[(size_t)n * CC];
        float s = 1.0f / (1.0f + expf(-x));
        float i2 = io * io;
        keys[i] = __float_as_uint(s * (i2 * i2 * i2));
    }
    __syncthreads();

    unsigned thrkey = 0u;
    int ncut = NN;

    if (count > KTOP) {
        // 4-bit radix select: exact 13th-largest key (order-invariant)
        if (tid == 0) { sprefix = 0u; sk = KTOP; }
        __syncthreads();
        for (int shift = 28; shift >= 0; shift -= 4) {
            if (tid < 16) hist[tid] = 0;
            __syncthreads();
            unsigned pref = sprefix;
            unsigned pmask = (shift == 28) ? 0u : (0xFFFFFFFFu << (shift + 4));
            for (int i = tid; i < count; i += 256) {
                unsigned key = keys[i];
                if ((key & pmask) == pref)
                    atomicAdd(&hist[(key >> shift) & 15], 1);
            }
            __syncthreads();
            if (tid == 0) {
                int kk = sk, cum = 0, d = 15;
                for (; d >= 0; --d) { cum += hist[d]; if (cum >= kk) break; }
                sk = kk - (cum - hist[d]);
                sE = hist[d];
                sprefix = pref | ((unsigned)d << shift);
            }
            __syncthreads();
        }
        thrkey = sprefix;
        const int kneed = sk, eq = sE;

        // boundary tie (bitwise-equal values at rank 13): cut by smallest n.
        // Effectively never triggers on continuous data; deterministic if it does.
        if (kneed < eq && thrkey > epskey) {
            int lo = 0, hi = NN - 1;
            while (lo < hi) {                 // block-uniform
                int mid = (lo + hi) >> 1;
                if (tid == 0) scount = 0;
                __syncthreads();
                for (int i = tid; i < count; i += 256)
                    if (keys[i] == thrkey && nnidx[i] <= mid) atomicAdd(&scount, 1);
                __syncthreads();
                if (scount >= kneed) hi = mid; else lo = mid + 1;
                __syncthreads();
            }
            ncut = lo;
        }
    }

    // emit positives: key > thr, or ==thr with n <= ncut; always key > EPS
    for (int i = tid; i < count; i += 256) {
        unsigned key = keys[i];
        bool sel = (key > thrkey || (key == thrkey && (int)nnidx[i] <= ncut)) &&
                   (key > epskey);
        if (sel) {
            int ai = b * NN + nnidx[i];
            atomicAdd(&cntb[ai], 1);
            atomicAdd(&mselb[ai], m);
            atomicAdd(&aselb[ai], __uint_as_float(key));
        }
    }
}

// Kernel 2: one thread per (b,n). Resolve assignment from scattered positives.
__global__ __launch_bounds__(256) void k_assign(
    const float* __restrict__ pd_scores, const float* __restrict__ pd_bboxes,
    const float* __restrict__ anc, const int* __restrict__ gt_labels,
    const float* __restrict__ gt_bboxes, const float* __restrict__ mask_gt,
    const int* __restrict__ cntb, const int* __restrict__ mselb,
    const float* __restrict__ aselb,
    float* __restrict__ out0, float* __restrict__ out1,
    float* __restrict__ out3, float* __restrict__ out4,
    float* __restrict__ perb)
{
    const int b = blockIdx.y;
    const int n = blockIdx.x * 256 + threadIdx.x;

    __shared__ float4 gtb[MM];
    __shared__ int    labS[MM];
    __shared__ float  mgS[MM];
    if (threadIdx.x < MM) {
        int m = threadIdx.x;
        gtb[m]  = *(const float4*)&gt_bboxes[(size_t)(b * MM + m) * 4];
        labS[m] = gt_labels[b * MM + m];
        mgS[m]  = mask_gt[b * MM + m];
    }
    __syncthreads();
    if (n >= NN) return;

    const size_t idx = (size_t)b * NN + n;
    const int cnt = cntb[idx];

    float per = 0.0f, fg = 0.0f;
    int mstar = 0;

    if (cnt > 0) {
        fg = 1.0f;
        const float4 p = *(const float4*)&pd_bboxes[idx * 4];
        if (cnt == 1) {
            mstar = mselb[idx];
            float a = aselb[idx];
            float io = iou_pair(gtb[mstar], p);   // positive => valid
            per = a / (a + FEPS) * io;
        } else {
            // multi-assigned: reference resolves by argmax IoU over valid m
            float2 a2 = *(const float2*)&anc[2 * n];
            float bestI = -1.0f; int bestM = 0;
            for (int m = 0; m < MM; ++m) {
                float4 gg = gtb[m];
                float d1 = a2.x - gg.x, d2 = a2.y - gg.y;
                float d3 = gg.z - a2.x, d4 = gg.w - a2.y;
                bool valid = (fminf(fminf(d1, d2), fminf(d3, d4)) > FEPS) &&
                             (mgS[m] > 0.5f);
                float io = valid ? iou_pair(gg, p) : 0.0f;
                if (io > bestI) { bestI = io; bestM = m; }   // first-max wins
            }
            mstar = bestM;
            float io = bestI;
            int lb = labS[mstar]; int lbc = lb > 0 ? lb : 0;
            float x = pd_scores[idx * CC + lbc];
            float s = 1.0f / (1.0f + expf(-x));
            float i2 = io * io;
            float a = s * (i2 * i2 * i2);      // continuous-only recompute
            per = a / (a + FEPS) * io;
        }
    }

    out0[idx] = (float)labS[mstar];
    ((float4*)out1)[idx] = gtb[mstar];
    out3[idx] = fg;
    out4[idx] = (float)mstar;
    perb[idx] = per;
}

// Kernel 3: fused zero + one-hot scatter, dense coalesced float4 writes.
__global__ __launch_bounds__(256) void k_cls(
    const float* __restrict__ out0, const float* __restrict__ perb,
    float4* __restrict__ cls4)
{
    int i = blockIdx.x * 256 + threadIdx.x;      // float4 index, C/4 = 20 per row
    if (i >= BB * NN * CC / 4) return;
    int row = i / 20;
    int c4 = (i - row * 20) * 4;
    int lab = (int)out0[row];
    float per = perb[row];
    int d = lab - c4;
    float4 v;
    v.x = (d == 0) ? per : 0.0f;
    v.y = (d == 1) ? per : 0.0f;
    v.z = (d == 2) ? per : 0.0f;
    v.w = (d == 3) ? per : 0.0f;
    cls4[i] = v;
}

extern "C" void kernel_launch(void* const* d_in, const int* in_sizes, int n_in,
                              void* d_out, int out_size, void* d_ws, size_t ws_size,
                              hipStream_t stream) {
    const float* pd_scores = (const float*)d_in[0];
    const float* pd_bboxes = (const float*)d_in[1];
    const float* anc       = (const float*)d_in[2];
    const int*   gt_labels = (const int*)d_in[3];
    const float* gt_bboxes = (const float*)d_in[4];
    const float* mask_gt   = (const float*)d_in[5];

    float* out  = (float*)d_out;
    float* out0 = out;
    float* out1 = out + OFF_O1;
    float* out2 = out + OFF_O2;
    float* out3 = out + OFF_O3;
    float* out4 = out + OFF_O4;

    // scratch in cls-region tail (overwritten by k_cls at the end)
    float* scr   = out2 + SCR_OFF;
    int*   cntb  = (int*)scr;
    int*   mselb = (int*)(scr + 134400);
    float* aselb = scr + 268800;
    float* perb  = (float*)d_ws;               // B*N floats

    // 0) zero the atomic scratch
    k_zero_scratch<<<dim3((403200 + 255) / 256), dim3(256), 0, stream>>>(
        (int*)scr, 403200);

    // 1) per-(b,m): compact, align, radix top-13, scatter positives
    k_select<<<dim3(BB * MM), dim3(256), 0, stream>>>(
        pd_scores, pd_bboxes, anc, gt_labels, gt_bboxes, mask_gt,
        cntb, mselb, aselb);

    // 2) per-anchor resolution
    k_assign<<<dim3((NN + 255) / 256, BB), dim3(256), 0, stream>>>(
        pd_scores, pd_bboxes, anc, gt_labels, gt_bboxes, mask_gt,
        cntb, mselb, aselb, out0, out1, out3, out4, perb);

    // 3) cls_targets: fused zero + scatter (dense coalesced write)
    const int n4 = (BB * NN * CC) / 4;
    k_cls<<<dim3((n4 + 255) / 256), dim3(256), 0, stream>>>(out0, perb, (float4*)out2);
}